// Round 13
// baseline (106.962 us; speedup 1.0000x reference)
//
#include <hip/hip_runtime.h>

#define N_NODES 100000
#define N_EDGES 1600000
#define D 64
#define BN_EPS 1e-5f
#define BK 64                          // dst nodes per fine bucket
#define NB ((N_NODES + BK - 1) / BK)   // 1563 fine buckets
#define NBK (NB * BK)                  // 100032 padded node count
#define FCAP 1280                      // fine bucket capacity (mean 1024, sd 32)
#define CSTRIDE 16                     // cursor stride (one per 64B line)
#define NREP 8                         // BN sum replicas
#define CHUNK 2048                     // edges per sort block
#define ABLOCKS ((N_EDGES + CHUNK - 1) / CHUNK)  // 782
#define NC 49                          // coarse buckets (dst >> 11)
#define BCH 17                         // max chunks per coarse bucket
#define CAPC (BCH * CHUNK)             // 34816 (mean 32768, sd 181)
#define NFB 32                         // fine bins per coarse bucket
#define NZERO (NC * CSTRIDE + NB * CSTRIDE + NREP * 128)  // ints to zero

typedef __attribute__((ext_vector_type(8))) short short8;
typedef __attribute__((ext_vector_type(4))) float f32x4;
typedef unsigned int uint;
typedef unsigned short ushort;

__device__ inline ushort f2bf(float f) {  // RNE fp32 -> bf16
  uint u = __float_as_uint(f);
  uint r = (u + 0x7fffu + ((u >> 16) & 1u)) >> 16;
  return (ushort)r;
}

// ---------------------------------------------------------------------------
// Zero the cursor/sums region.
// ---------------------------------------------------------------------------
__global__ __launch_bounds__(256) void zero_kernel(uint4* __restrict__ p) {
  int i = blockIdx.x * 256 + threadIdx.x;
  if (i < NZERO / 4) p[i] = make_uint4(0, 0, 0, 0);
}

// ---------------------------------------------------------------------------
// Pass A: LDS counting sort of 2048 edges into 49 coarse buckets (dst>>11),
// appended contiguously per bucket (coalesced). Per-wave histograms/cursors.
// Fused tails: x -> QUARTER-MAJOR bf16 regions xbq[4][NBK][16 feats] (each
// region 3.2MB -> fits one XCD L2); B-fragment prepack.
// ---------------------------------------------------------------------------
__global__ __launch_bounds__(256) void passA_kernel(
    const float* __restrict__ x, const int* __restrict__ ei,
    const float* __restrict__ Wl, const float* __restrict__ Wr,
    int* __restrict__ ccur, uint* __restrict__ cstg,
    uint4* __restrict__ xbq4, uint4* __restrict__ wfrag) {
  __shared__ uint sent[CHUNK];
  __shared__ unsigned char sbin[CHUNK];
  __shared__ int hist[4][64], offs[64], cur[4][64], gbase[64];

  const int tid = threadIdx.x;
  const int w = tid >> 6;
  const int bid = blockIdx.x;
  hist[w][tid & 63] = 0;
  __syncthreads();

  const int e0 = bid * CHUNK;
  const int m = min(CHUNK, N_EDGES - e0);
  uint ent[8];
  int bin[8];
#pragma unroll
  for (int r = 0; r < 8; ++r) {
    int i = tid + r * 256;
    if (i < m) {
      int s = ei[e0 + i];
      int d = ei[N_EDGES + e0 + i];
      bin[r] = d >> 11;
      ent[r] = (uint)s | ((uint)(d & 2047) << 17);
      atomicAdd(&hist[w][bin[r]], 1);
    } else {
      bin[r] = -1;
    }
  }
  __syncthreads();
  if (tid < 64) {  // wave-0 scan over 64 bins
    int h0 = hist[0][tid], h1 = hist[1][tid], h2 = hist[2][tid], h3 = hist[3][tid];
    int c = h0 + h1 + h2 + h3;
    int incl = c;
#pragma unroll
    for (int off = 1; off < 64; off <<= 1) {
      int t = __shfl_up(incl, off, 64);
      if (tid >= off) incl += t;
    }
    int o = incl - c;
    offs[tid] = o;
    gbase[tid] = c ? atomicAdd(&ccur[tid * CSTRIDE], c) : 0;
    cur[0][tid] = o;
    cur[1][tid] = o + h0;
    cur[2][tid] = o + h0 + h1;
    cur[3][tid] = o + h0 + h1 + h2;
  }
  __syncthreads();
#pragma unroll
  for (int r = 0; r < 8; ++r) {
    if (bin[r] >= 0) {
      int sl = atomicAdd(&cur[w][bin[r]], 1);
      sent[sl] = ent[r];
      sbin[sl] = (unsigned char)bin[r];
    }
  }
  __syncthreads();
  for (int i = tid; i < m; i += 256) {  // coalesced append per bucket run
    int b = sbin[i];
    int dp = gbase[b] + (i - offs[b]);
    if (dp < CAPC) cstg[(size_t)b * CAPC + dp] = sent[i];
  }

  // fused x -> quarter-major bf16 (zeros for pad nodes N..NBK incl. dummy)
  for (int i = bid * 256 + tid; i < NBK * 8; i += ABLOCKS * 256) {
    int n = i >> 3, s = i & 7;          // node, 8-feature segment
    int q = s >> 1, hf = s & 1;         // quarter, half-of-quarter
    uint4 o = make_uint4(0, 0, 0, 0);
    if (n < N_NODES) {
      const float4* xf = (const float4*)x;
      float4 v0 = xf[n * 16 + s * 2], v1 = xf[n * 16 + s * 2 + 1];
      o.x = ((uint)f2bf(v0.y) << 16) | f2bf(v0.x);
      o.y = ((uint)f2bf(v0.w) << 16) | f2bf(v0.z);
      o.z = ((uint)f2bf(v1.y) << 16) | f2bf(v1.x);
      o.w = ((uint)f2bf(v1.w) << 16) | f2bf(v1.z);
    }
    xbq4[((size_t)q * NBK + n) * 2 + hf] = o;
  }

  // fused B-fragment prepack: wfrag[mat][ct][kk][lane]; lane l holds
  // k = kk*32 + (l>>4)*8 + i, col = ct*16 + (l&15).
  if (bid < 4) {
    int e = bid * 256 + tid;  // 0..1023
    int mat = e >> 9, r = e & 511;
    int ct = r >> 7, kk = (r >> 6) & 1, l = r & 63;
    int col = ct * 16 + (l & 15);
    int k0 = kk * 32 + (l >> 4) * 8;
    const float* W = mat ? Wr : Wl;
    short8 sv;
#pragma unroll
    for (int i = 0; i < 8; ++i) sv[i] = (short)f2bf(W[col * 64 + k0 + i]);
    wfrag[e] = *(uint4*)&sv;
  }
}

// ---------------------------------------------------------------------------
// Pass B: refine each coarse bucket into 32 fine buckets of 64 dst nodes.
// Out entry = src | dst_local6<<17.
// ---------------------------------------------------------------------------
__global__ __launch_bounds__(256) void passB_kernel(
    const uint* __restrict__ cstg, const int* __restrict__ ccur,
    int* __restrict__ fcur, uint* __restrict__ fstg) {
  __shared__ uint sent[CHUNK];
  __shared__ unsigned char sbin[CHUNK];
  __shared__ int hist[4][NFB], offs[NFB], cur[4][NFB], gbase[NFB];

  const int tid = threadIdx.x;
  const int w = tid >> 6;
  const int cb = blockIdx.x / BCH;
  const int ch = blockIdx.x % BCH;
  int cntc = ccur[cb * CSTRIDE];
  cntc = cntc < CAPC ? cntc : CAPC;
  const int e0 = ch * CHUNK;
  int m = cntc - e0;
  if (m <= 0) return;  // block-uniform
  if (m > CHUNK) m = CHUNK;

  if ((tid & 63) < NFB) hist[w][tid & 63] = 0;
  __syncthreads();

  const uint* sb = cstg + (size_t)cb * CAPC + e0;
  uint ent[8];
  int bin[8];
#pragma unroll
  for (int r = 0; r < 8; ++r) {
    int i = tid + r * 256;
    if (i < m) {
      uint e = sb[i];
      uint d11 = e >> 17;
      bin[r] = (int)(d11 >> 6);
      ent[r] = (e & 0x1FFFFu) | ((d11 & 63u) << 17);
      atomicAdd(&hist[w][bin[r]], 1);
    } else {
      bin[r] = -1;
    }
  }
  __syncthreads();
  if (tid < 64) {  // wave-0 scan over NFB bins
    int h0 = 0, h1 = 0, h2 = 0, h3 = 0, c = 0;
    if (tid < NFB) {
      h0 = hist[0][tid]; h1 = hist[1][tid]; h2 = hist[2][tid]; h3 = hist[3][tid];
      c = h0 + h1 + h2 + h3;
    }
    int incl = c;
#pragma unroll
    for (int off = 1; off < 64; off <<= 1) {
      int t = __shfl_up(incl, off, 64);
      if (tid >= off) incl += t;
    }
    if (tid < NFB) {
      int o = incl - c;
      offs[tid] = o;
      gbase[tid] = c ? atomicAdd(&fcur[(cb * NFB + tid) * CSTRIDE], c) : 0;
      cur[0][tid] = o;
      cur[1][tid] = o + h0;
      cur[2][tid] = o + h0 + h1;
      cur[3][tid] = o + h0 + h1 + h2;
    }
  }
  __syncthreads();
#pragma unroll
  for (int r = 0; r < 8; ++r) {
    if (bin[r] >= 0) {
      int sl = atomicAdd(&cur[w][bin[r]], 1);
      sent[sl] = ent[r];
      sbin[sl] = (unsigned char)bin[r];
    }
  }
  __syncthreads();
  for (int i = tid; i < m; i += 256) {
    int b = sbin[i];
    int dp = gbase[b] + (i - offs[b]);
    if (dp < FCAP) fstg[(size_t)(cb * NFB + b) * FCAP + dp] = sent[i];
  }
}

// ---------------------------------------------------------------------------
// GatherQ: one block per (bucket, quarter). quarter = (blockIdx%8)>>1 pins
// each feature quarter (3.2MB region) to one XCD pair via round-robin
// dispatch -> random row reads become L2-resident. Per block: LDS bin-sort
// of the bucket's edges (x4-padded with dummy id), then 4-lane groups own a
// node each; lane reads uint2 (4 feats) per neighbor row; bf16 mean ->
// meanq[q][node][16].
// ---------------------------------------------------------------------------
__global__ __launch_bounds__(256) void gatherq_kernel(
    const uint2* __restrict__ xq2,     // [4][NBK][4] uint2 quarter rows
    const uint* __restrict__ staged,
    const int* __restrict__ fcur,
    uint2* __restrict__ meanq2) {      // same geometry as xq2
  __shared__ __align__(16) int ids[FCAP + 3 * BK + 16];
  __shared__ int hh[4][BK];
  __shared__ int hcnt[BK], boff[BK];
  __shared__ int wcur[4][BK];

  const int tid = threadIdx.x;
  const int lane = tid & 63;
  const int w = tid >> 6;
  const int xcd = blockIdx.x & 7;
  const int q = xcd >> 1;
  const int bucket = 2 * (blockIdx.x >> 3) + (xcd & 1);
  if (bucket >= NB) return;

  hh[w][lane] = 0;
  __syncthreads();

  int bc = fcur[bucket * CSTRIDE];
  const int bcount = bc < FCAP ? bc : FCAP;
  const uint* sbase = staged + (size_t)bucket * FCAP;

  uint entv[5];
#pragma unroll
  for (int k = 0; k < 5; ++k) {
    int i = tid + k * 256;
    if (i < bcount) {
      entv[k] = sbase[i];
      atomicAdd(&hh[w][entv[k] >> 17], 1);
    } else {
      entv[k] = 0xFFFFFFFFu;
    }
  }
  __syncthreads();

  if (w == 0) {  // scan x4-padded counts; fill pads with dummy id (zeros row)
    int h0 = hh[0][lane], h1 = hh[1][lane], h2 = hh[2][lane], h3 = hh[3][lane];
    int c = h0 + h1 + h2 + h3;
    int p4 = (c + 3) & ~3;
    int incl = p4;
#pragma unroll
    for (int off = 1; off < 64; off <<= 1) {
      int t = __shfl_up(incl, off, 64);
      if (lane >= off) incl += t;
    }
    int start = incl - p4;
    hcnt[lane] = c;
    boff[lane] = start;
    wcur[0][lane] = start;
    wcur[1][lane] = start + h0;
    wcur[2][lane] = start + h0 + h1;
    wcur[3][lane] = start + h0 + h1 + h2;
    for (int t2 = c; t2 < p4; ++t2) ids[start + t2] = N_NODES;
  }
  __syncthreads();

#pragma unroll
  for (int k = 0; k < 5; ++k) {
    if (entv[k] != 0xFFFFFFFFu) {
      int dl = entv[k] >> 17;
      int pos = atomicAdd(&wcur[w][dl], 1);
      ids[pos] = (int)(entv[k] & 0x1FFFFu);
    }
  }
  __syncthreads();

  // ---- gather quarter q: 4-lane group g owns node w*16+g ----
  const int q2l = lane & 3;   // which uint2 (4 feats) of the 32B quarter row
  const int g = lane >> 2;
  const int row = w * 16 + g;
  const int dgv = hcnt[row];
  const int off = boff[row];
  const int dg4 = (dgv + 3) & ~3;
  const int rbase = q * NBK;
  float a0 = 0.f, a1 = 0.f, a2 = 0.f, a3 = 0.f;
  for (int j = 0; j < dg4; j += 4) {
    int4 sv = *(const int4*)&ids[off + j];  // one ds_read_b128
    uint2 r0 = xq2[(uint)(rbase + sv.x) * 4u + (uint)q2l];
    uint2 r1 = xq2[(uint)(rbase + sv.y) * 4u + (uint)q2l];
    uint2 r2 = xq2[(uint)(rbase + sv.z) * 4u + (uint)q2l];
    uint2 r3 = xq2[(uint)(rbase + sv.w) * 4u + (uint)q2l];
    a0 += __uint_as_float(r0.x << 16); a1 += __uint_as_float(r0.x & 0xffff0000u);
    a2 += __uint_as_float(r0.y << 16); a3 += __uint_as_float(r0.y & 0xffff0000u);
    a0 += __uint_as_float(r1.x << 16); a1 += __uint_as_float(r1.x & 0xffff0000u);
    a2 += __uint_as_float(r1.y << 16); a3 += __uint_as_float(r1.y & 0xffff0000u);
    a0 += __uint_as_float(r2.x << 16); a1 += __uint_as_float(r2.x & 0xffff0000u);
    a2 += __uint_as_float(r2.y << 16); a3 += __uint_as_float(r2.y & 0xffff0000u);
    a0 += __uint_as_float(r3.x << 16); a1 += __uint_as_float(r3.x & 0xffff0000u);
    a2 += __uint_as_float(r3.y << 16); a3 += __uint_as_float(r3.y & 0xffff0000u);
  }
  float inv = 1.0f / fmaxf((float)dgv, 1.0f);
  uint2 o;
  o.x = ((uint)f2bf(a1 * inv) << 16) | f2bf(a0 * inv);
  o.y = ((uint)f2bf(a3 * inv) << 16) | f2bf(a2 * inv);
  meanq2[(uint)(rbase + bucket * BK + row) * 4u + (uint)q2l] = o;
}

// ---------------------------------------------------------------------------
// Transform: one block per bucket; wave w -> 16 nodes. MFMA fragments load
// directly from quarter-major mean/x regions (8 feats = one dwordx4).
// h -> bf16 via LDS repack; BN partial sums -> replicated accumulators.
// ---------------------------------------------------------------------------
__global__ __launch_bounds__(256) void transform_kernel(
    const uint4* __restrict__ xbq4,
    const uint4* __restrict__ meanq4,
    const uint4* __restrict__ wfrag,
    const float* __restrict__ bl,
    uint4* __restrict__ hb4,           // [NBK][8] bf16 h rows
    float* __restrict__ sums) {        // [NREP][128]
  __shared__ __align__(16) uint hslab[4][520];
  __shared__ float bsum[D], bsq[D];

  const int tid = threadIdx.x;
  const int lane = tid & 63;
  const int w = tid >> 6;
  const int bid = blockIdx.x;

  if (tid < D) { bsum[tid] = 0.f; bsq[tid] = 0.f; }
  __syncthreads();

  short8 bf[2][4][2];
#pragma unroll
  for (int mat = 0; mat < 2; ++mat)
#pragma unroll
    for (int ct = 0; ct < 4; ++ct)
#pragma unroll
      for (int kk = 0; kk < 2; ++kk) {
        uint4 v = wfrag[((mat * 4 + ct) * 2 + kk) * 64 + lane];
        bf[mat][ct][kk] = *(short8*)&v;
      }

  const int r16 = lane & 15;
  const int kg = lane >> 4;
  const int gn0 = bid * BK + w * 16;
  float psum[4] = {0.f, 0.f, 0.f, 0.f};
  float psq[4] = {0.f, 0.f, 0.f, 0.f};

  if (gn0 < N_NODES) {
    const int n = gn0 + r16;
    const int qlo = kg >> 1, hf = kg & 1;  // fragment = feats kg*8..kg*8+7
    uint4 vm0 = meanq4[((size_t)qlo * NBK + n) * 2 + hf];
    uint4 vm1 = meanq4[((size_t)(2 + qlo) * NBK + n) * 2 + hf];
    uint4 vx0 = xbq4[((size_t)qlo * NBK + n) * 2 + hf];
    uint4 vx1 = xbq4[((size_t)(2 + qlo) * NBK + n) * 2 + hf];
    short8 am0 = *(short8*)&vm0, am1 = *(short8*)&vm1;
    short8 ax0 = *(short8*)&vx0, ax1 = *(short8*)&vx1;

    ushort* hl = (ushort*)&hslab[w][0];  // 16 rows x 64 u16
#pragma unroll
    for (int ct = 0; ct < 4; ++ct) {
      float bias = bl[ct * 16 + r16];
      f32x4 acc = {0.f, 0.f, 0.f, 0.f};
      acc = __builtin_amdgcn_mfma_f32_16x16x32_bf16(am0, bf[0][ct][0], acc, 0, 0, 0);
      acc = __builtin_amdgcn_mfma_f32_16x16x32_bf16(am1, bf[0][ct][1], acc, 0, 0, 0);
      acc = __builtin_amdgcn_mfma_f32_16x16x32_bf16(ax0, bf[1][ct][0], acc, 0, 0, 0);
      acc = __builtin_amdgcn_mfma_f32_16x16x32_bf16(ax1, bf[1][ct][1], acc, 0, 0, 0);
#pragma unroll
      for (int r = 0; r < 4; ++r) {
        float hv = fmaxf(acc[r] + bias, 0.f);
        hl[(kg * 4 + r) * 64 + ct * 16 + r16] = f2bf(hv);
        psum[ct] += hv;
        psq[ct] += hv * hv;
      }
    }
    const uint4* hsl = (const uint4*)&hslab[w][0];
    uint4 v0 = hsl[lane];
    uint4 v1 = hsl[64 + lane];
    hb4[(size_t)(gn0 + (lane >> 3)) * 8 + (lane & 7)] = v0;
    hb4[(size_t)(gn0 + 8 + (lane >> 3)) * 8 + (lane & 7)] = v1;
  }

#pragma unroll
  for (int ct = 0; ct < 4; ++ct) {
    float v1 = psum[ct], v2 = psq[ct];
    v1 += __shfl_xor(v1, 16, 64); v1 += __shfl_xor(v1, 32, 64);
    v2 += __shfl_xor(v2, 16, 64); v2 += __shfl_xor(v2, 32, 64);
    if (lane < 16) {
      atomicAdd(&bsum[ct * 16 + lane], v1);
      atomicAdd(&bsq[ct * 16 + lane], v2);
    }
  }
  __syncthreads();
  if (tid < D) {
    float* srep = sums + (size_t)(bid & (NREP - 1)) * 128;
    atomicAdd(&srep[tid], bsum[tid]);
    atomicAdd(&srep[D + tid], bsq[tid]);
  }
}

// ---------------------------------------------------------------------------
// finalize: reduce BN replicas -> scale/shift; out = x + h*scale + shift.
// ---------------------------------------------------------------------------
__global__ __launch_bounds__(256) void finalize_kernel(
    const float* __restrict__ x,
    const uint4* __restrict__ hb4,
    const float* __restrict__ sums,
    const float* __restrict__ gamma,
    const float* __restrict__ beta,
    float* __restrict__ out) {
  __shared__ float ssc[D], ssh[D];
  const int tid = threadIdx.x;
  if (tid < D) {
    float s = 0.f, q = 0.f;
#pragma unroll
    for (int r = 0; r < NREP; ++r) {
      s += sums[r * 128 + tid];
      q += sums[r * 128 + D + tid];
    }
    float mu = s / (float)N_NODES;
    float var = q / (float)N_NODES - mu * mu;
    float inv = rsqrtf(fmaxf(var, 0.f) + BN_EPS);
    float sc = gamma[tid] * inv;
    ssc[tid] = sc;
    ssh[tid] = beta[tid] - mu * sc;
  }
  __syncthreads();
  const int total = N_NODES * D / 8;  // 8 feats per thread
  int i = blockIdx.x * 256 + tid;
  if (i >= total) return;
  int u8 = i & 7;
  float4 sa = *(const float4*)&ssc[u8 * 8];
  float4 sb = *(const float4*)&ssc[u8 * 8 + 4];
  float4 ha = *(const float4*)&ssh[u8 * 8];
  float4 hbv = *(const float4*)&ssh[u8 * 8 + 4];
  uint4 h = hb4[i];
  float4 x0 = ((const float4*)x)[i * 2];
  float4 x1 = ((const float4*)x)[i * 2 + 1];
  float4 r0, r1;
  r0.x = x0.x + __uint_as_float(h.x << 16) * sa.x + ha.x;
  r0.y = x0.y + __uint_as_float(h.x & 0xffff0000u) * sa.y + ha.y;
  r0.z = x0.z + __uint_as_float(h.y << 16) * sa.z + ha.z;
  r0.w = x0.w + __uint_as_float(h.y & 0xffff0000u) * sa.w + ha.w;
  r1.x = x1.x + __uint_as_float(h.z << 16) * sb.x + hbv.x;
  r1.y = x1.y + __uint_as_float(h.z & 0xffff0000u) * sb.y + hbv.y;
  r1.z = x1.z + __uint_as_float(h.w << 16) * sb.z + hbv.z;
  r1.w = x1.w + __uint_as_float(h.w & 0xffff0000u) * sb.w + hbv.w;
  ((float4*)out)[i * 2] = r0;
  ((float4*)out)[i * 2 + 1] = r1;
}

extern "C" void kernel_launch(void* const* d_in, const int* in_sizes, int n_in,
                              void* d_out, int out_size, void* d_ws, size_t ws_size,
                              hipStream_t stream) {
  const float* x     = (const float*)d_in[0];
  const int*   ei    = (const int*)d_in[1];
  const float* Wl    = (const float*)d_in[2];
  const float* bl    = (const float*)d_in[3];
  const float* Wr    = (const float*)d_in[4];
  const float* gamma = (const float*)d_in[5];
  const float* beta  = (const float*)d_in[6];
  float* out = (float*)d_out;

  // workspace layout (4B units); zeroed region first; 16B alignment kept.
  int* ccur   = (int*)d_ws;                        // NC*CSTRIDE  (zeroed)
  int* fcur   = ccur + NC * CSTRIDE;               // NB*CSTRIDE  (zeroed)
  float* sums = (float*)(fcur + NB * CSTRIDE);     // NREP*128    (zeroed)
  uint* cstg  = (uint*)(sums + NREP * 128);        // NC*CAPC
  uint* fstg  = cstg + (size_t)NC * CAPC;          // NB*FCAP
  uint* xbq   = fstg + (size_t)NB * FCAP;          // 4*NBK*8 (quarter-major)
  uint* meanq = xbq + (size_t)4 * NBK * 8;         // 4*NBK*8
  uint* wfrag = meanq + (size_t)4 * NBK * 8;       // 1024*4
  uint* hb    = wfrag + 1024 * 4;                  // NBK*32 (bf16 h rows)

  zero_kernel<<<(NZERO / 4 + 255) / 256, 256, 0, stream>>>((uint4*)d_ws);
  passA_kernel<<<ABLOCKS, 256, 0, stream>>>(x, ei, Wl, Wr, ccur, cstg,
                                            (uint4*)xbq, (uint4*)wfrag);
  passB_kernel<<<NC * BCH, 256, 0, stream>>>(cstg, ccur, fcur, fstg);
  gatherq_kernel<<<8 * 782, 256, 0, stream>>>(
      (const uint2*)xbq, fstg, fcur, (uint2*)meanq);
  transform_kernel<<<NB, 256, 0, stream>>>(
      (const uint4*)xbq, (const uint4*)meanq, (const uint4*)wfrag, bl,
      (uint4*)hb, sums);
  finalize_kernel<<<(N_NODES * D / 8 + 255) / 256, 256, 0, stream>>>(
      x, (const uint4*)hb, sums, gamma, beta, out);
}

// Round 16
// 88.327 us; speedup vs baseline: 1.2110x; 1.2110x over previous
//
#include <hip/hip_runtime.h>

#define N_NODES 100000
#define N_EDGES 1600000
#define D 64
#define BN_EPS 1e-5f
#define BK 64                          // dst nodes per fine bucket
#define NB ((N_NODES + BK - 1) / BK)   // 1563 fine buckets
#define FCAP 1280                      // fine bucket capacity (mean 1024, sd 32)
#define CSTRIDE 16                     // cursor stride (one per 64B line)
#define NREP 8                         // BN sum replicas
#define CHUNK 2048                     // edges per sort block
#define ABLOCKS ((N_EDGES + CHUNK - 1) / CHUNK)  // 782
#define NC 49                          // coarse buckets (dst >> 11)
#define BCH 17                         // max chunks per coarse bucket
#define CAPC (BCH * CHUNK)             // 34816 (mean 32768, sd 181)
#define NFB 32                         // fine bins per coarse bucket
#define NZERO (NC * CSTRIDE + NB * CSTRIDE + NREP * 128)  // ints to zero

typedef __attribute__((ext_vector_type(8))) short short8;
typedef __attribute__((ext_vector_type(4))) float f32x4;
typedef unsigned int uint;
typedef unsigned short ushort;

__device__ inline ushort f2bf(float f) {  // RNE fp32 -> bf16
  uint u = __float_as_uint(f);
  uint r = (u + 0x7fffu + ((u >> 16) & 1u)) >> 16;
  return (ushort)r;
}

// biased-u8 encode: code = round(x*32) + 128 in [1,255]; value 0 -> 128.
// Sum of codes - 128*count = sum of round(x*32) exactly (quant err <= 1/64).
__device__ inline uint f2u8(float f) {
  float c = fminf(fmaxf(f * 32.f, -127.f), 127.f);
  return (uint)(int)(rintf(c) + 128.f);
}

// ---------------------------------------------------------------------------
// Zero the cursor/sums region (fast replacement for rocclr fillBuffer).
// ---------------------------------------------------------------------------
__global__ __launch_bounds__(256) void zero_kernel(uint4* __restrict__ p) {
  int i = blockIdx.x * 256 + threadIdx.x;
  if (i < NZERO / 4) p[i] = make_uint4(0, 0, 0, 0);
}

// ---------------------------------------------------------------------------
// Pass A: block-local LDS counting sort of 2048 edges into 49 coarse buckets
// (dst>>11), appended contiguously per bucket (coalesced writes). Per-wave
// histograms/cursors. Entry = src | dst11<<17.
// Fused tails: x -> bf16 rows AND biased-u8 rows (64B); B-frag prepack.
// ---------------------------------------------------------------------------
__global__ __launch_bounds__(256) void passA_kernel(
    const float* __restrict__ x, const int* __restrict__ ei,
    const float* __restrict__ Wl, const float* __restrict__ Wr,
    int* __restrict__ ccur, uint* __restrict__ cstg,
    uint4* __restrict__ xb4, uint2* __restrict__ xq2,
    uint4* __restrict__ wfrag) {
  __shared__ uint sent[CHUNK];
  __shared__ unsigned char sbin[CHUNK];
  __shared__ int hist[4][64], offs[64], cur[4][64], gbase[64];

  const int tid = threadIdx.x;
  const int w = tid >> 6;
  const int bid = blockIdx.x;
  hist[w][tid & 63] = 0;
  __syncthreads();

  const int e0 = bid * CHUNK;
  const int m = min(CHUNK, N_EDGES - e0);
  uint ent[8];
  int bin[8];
#pragma unroll
  for (int r = 0; r < 8; ++r) {
    int i = tid + r * 256;
    if (i < m) {
      int s = ei[e0 + i];
      int d = ei[N_EDGES + e0 + i];
      bin[r] = d >> 11;
      ent[r] = (uint)s | ((uint)(d & 2047) << 17);
      atomicAdd(&hist[w][bin[r]], 1);
    } else {
      bin[r] = -1;
    }
  }
  __syncthreads();
  if (tid < 64) {  // wave-0 scan over 64 bins
    int h0 = hist[0][tid], h1 = hist[1][tid], h2 = hist[2][tid], h3 = hist[3][tid];
    int c = h0 + h1 + h2 + h3;
    int incl = c;
#pragma unroll
    for (int off = 1; off < 64; off <<= 1) {
      int t = __shfl_up(incl, off, 64);
      if (tid >= off) incl += t;
    }
    int o = incl - c;
    offs[tid] = o;
    gbase[tid] = c ? atomicAdd(&ccur[tid * CSTRIDE], c) : 0;
    cur[0][tid] = o;
    cur[1][tid] = o + h0;
    cur[2][tid] = o + h0 + h1;
    cur[3][tid] = o + h0 + h1 + h2;
  }
  __syncthreads();
#pragma unroll
  for (int r = 0; r < 8; ++r) {
    if (bin[r] >= 0) {
      int sl = atomicAdd(&cur[w][bin[r]], 1);
      sent[sl] = ent[r];
      sbin[sl] = (unsigned char)bin[r];
    }
  }
  __syncthreads();
  for (int i = tid; i < m; i += 256) {  // coalesced append per bucket run
    int b = sbin[i];
    int dp = gbase[b] + (i - offs[b]);
    if (dp < CAPC) cstg[(size_t)b * CAPC + dp] = sent[i];
  }

  // fused x -> bf16 + biased-u8 convert (+ dummy row at id N_NODES:
  // bf16 zeros; u8 0x80 bytes = value 0 under the bias)
  for (int i = bid * 256 + tid; i < N_NODES * D / 8 + 8; i += ABLOCKS * 256) {
    if (i < N_NODES * D / 8) {
      const float4* xf = (const float4*)x;
      float4 v0 = xf[i * 2], v1 = xf[i * 2 + 1];
      uint4 o;
      o.x = ((uint)f2bf(v0.y) << 16) | f2bf(v0.x);
      o.y = ((uint)f2bf(v0.w) << 16) | f2bf(v0.z);
      o.z = ((uint)f2bf(v1.y) << 16) | f2bf(v1.x);
      o.w = ((uint)f2bf(v1.w) << 16) | f2bf(v1.z);
      xb4[i] = o;
      uint2 q;
      q.x = f2u8(v0.x) | (f2u8(v0.y) << 8) | (f2u8(v0.z) << 16) | (f2u8(v0.w) << 24);
      q.y = f2u8(v1.x) | (f2u8(v1.y) << 8) | (f2u8(v1.z) << 16) | (f2u8(v1.w) << 24);
      xq2[i] = q;
    } else {
      xb4[i] = make_uint4(0, 0, 0, 0);
      xq2[i] = make_uint2(0x80808080u, 0x80808080u);
    }
  }

  // fused B-fragment prepack: wfrag[mat][ct][kk][lane]; lane l holds
  // k = kk*32 + (l>>4)*8 + i, col = ct*16 + (l&15).
  if (bid < 4) {
    int e = bid * 256 + tid;  // 0..1023
    int mat = e >> 9, r = e & 511;
    int ct = r >> 7, kk = (r >> 6) & 1, l = r & 63;
    int col = ct * 16 + (l & 15);
    int k0 = kk * 32 + (l >> 4) * 8;
    const float* W = mat ? Wr : Wl;
    short8 sv;
#pragma unroll
    for (int i = 0; i < 8; ++i) sv[i] = (short)f2bf(W[col * 64 + k0 + i]);
    wfrag[e] = *(uint4*)&sv;
  }
}

// ---------------------------------------------------------------------------
// Pass B: refine each coarse bucket into 32 fine buckets of 64 dst nodes.
// Out entry = src | dst_local6<<17.
// ---------------------------------------------------------------------------
__global__ __launch_bounds__(256) void passB_kernel(
    const uint* __restrict__ cstg, const int* __restrict__ ccur,
    int* __restrict__ fcur, uint* __restrict__ fstg) {
  __shared__ uint sent[CHUNK];
  __shared__ unsigned char sbin[CHUNK];
  __shared__ int hist[4][NFB], offs[NFB], cur[4][NFB], gbase[NFB];

  const int tid = threadIdx.x;
  const int w = tid >> 6;
  const int cb = blockIdx.x / BCH;
  const int ch = blockIdx.x % BCH;
  int cntc = ccur[cb * CSTRIDE];
  cntc = cntc < CAPC ? cntc : CAPC;
  const int e0 = ch * CHUNK;
  int m = cntc - e0;
  if (m <= 0) return;  // block-uniform
  if (m > CHUNK) m = CHUNK;

  if ((tid & 63) < NFB) hist[w][tid & 63] = 0;
  __syncthreads();

  const uint* sb = cstg + (size_t)cb * CAPC + e0;
  uint ent[8];
  int bin[8];
#pragma unroll
  for (int r = 0; r < 8; ++r) {
    int i = tid + r * 256;
    if (i < m) {
      uint e = sb[i];
      uint d11 = e >> 17;
      bin[r] = (int)(d11 >> 6);
      ent[r] = (e & 0x1FFFFu) | ((d11 & 63u) << 17);
      atomicAdd(&hist[w][bin[r]], 1);
    } else {
      bin[r] = -1;
    }
  }
  __syncthreads();
  if (tid < 64) {  // wave-0 scan over NFB bins
    int h0 = 0, h1 = 0, h2 = 0, h3 = 0, c = 0;
    if (tid < NFB) {
      h0 = hist[0][tid]; h1 = hist[1][tid]; h2 = hist[2][tid]; h3 = hist[3][tid];
      c = h0 + h1 + h2 + h3;
    }
    int incl = c;
#pragma unroll
    for (int off = 1; off < 64; off <<= 1) {
      int t = __shfl_up(incl, off, 64);
      if (tid >= off) incl += t;
    }
    if (tid < NFB) {
      int o = incl - c;
      offs[tid] = o;
      gbase[tid] = c ? atomicAdd(&fcur[(cb * NFB + tid) * CSTRIDE], c) : 0;
      cur[0][tid] = o;
      cur[1][tid] = o + h0;
      cur[2][tid] = o + h0 + h1;
      cur[3][tid] = o + h0 + h1 + h2;
    }
  }
  __syncthreads();
#pragma unroll
  for (int r = 0; r < 8; ++r) {
    if (bin[r] >= 0) {
      int sl = atomicAdd(&cur[w][bin[r]], 1);
      sent[sl] = ent[r];
      sbin[sl] = (unsigned char)bin[r];
    }
  }
  __syncthreads();
  for (int i = tid; i < m; i += 256) {
    int b = sbin[i];
    int dp = gbase[b] + (i - offs[b]);
    if (dp < FCAP) fstg[(size_t)(cb * NFB + b) * FCAP + dp] = sent[i];
  }
}

// ---------------------------------------------------------------------------
// Pass 2: one 256-thread block per fine bucket of 64 dst nodes.
//   bin:    LDS counting sort by dst_local; bins padded x4 with dummy id so
//           the gather reads ids as one aligned int4 (ds_read_b128).
//   gather: 4-lane group owns ONE node; row is biased-u8 (64B = ONE cache
//           line -> half the per-line address-divergence cost of 128B bf16).
//           Lane loads uint4 (16 feats); exact uint32 accumulate via plain
//           byte extraction; un-bias once at the end -> bf16 mean.
//   mfma:   B-frags from prepacked global table; h written fp32 directly to
//           d_out (r7-proven epilogue; no extra h buffer -> no overflow).
// ---------------------------------------------------------------------------
__global__ __launch_bounds__(256) void bucket_bin_gather_mfma_kernel(
    const uint* __restrict__ xb,       // [N+1][32] packed bf16 pairs
    const uint4* __restrict__ xq4,     // [N+1][4]  biased-u8 rows (64B)
    const uint* __restrict__ staged,
    const int* __restrict__ fcur,
    const uint4* __restrict__ wfrag,   // [2][4][2][64] prepacked B-frags
    const float* __restrict__ bl,
    float* __restrict__ hout,          // = d_out, pre-BN h (fp32)
    float* __restrict__ sums) {        // [NREP][128] replicated (sum, sumsq)
  __shared__ __align__(16) int ids[FCAP + 3 * BK + 16];  // padded binned ids
  __shared__ int hh[4][BK];                        // per-wave histograms
  __shared__ int hcnt[BK], boff[BK];
  __shared__ int wcur[4][BK];                      // per-wave scatter cursors
  __shared__ __align__(16) uint smean[4][16 * 36]; // per-wave mean slabs
  __shared__ float bsum[D], bsq[D];

  const int tid = threadIdx.x;
  const int lane = tid & 63;
  const int w = tid >> 6;
  const int bid = blockIdx.x;

  hh[w][lane] = 0;
  if (tid < D) { bsum[tid] = 0.f; bsq[tid] = 0.f; }
  __syncthreads();

  int bc = fcur[bid * CSTRIDE];
  const int bcount = bc < FCAP ? bc : FCAP;
  const uint* sbase = staged + (size_t)bid * FCAP;

  uint entv[5];
#pragma unroll
  for (int k = 0; k < 5; ++k) {
    int i = tid + k * 256;
    if (i < bcount) {
      entv[k] = sbase[i];
      atomicAdd(&hh[w][entv[k] >> 17], 1);
    } else {
      entv[k] = 0xFFFFFFFFu;
    }
  }
  __syncthreads();

  if (w == 0) {  // scan x4-PADDED counts; fill pads with dummy id; cursors
    int h0 = hh[0][lane], h1 = hh[1][lane], h2 = hh[2][lane], h3 = hh[3][lane];
    int c = h0 + h1 + h2 + h3;
    int p4 = (c + 3) & ~3;
    int incl = p4;
#pragma unroll
    for (int off = 1; off < 64; off <<= 1) {
      int t = __shfl_up(incl, off, 64);
      if (lane >= off) incl += t;
    }
    int start = incl - p4;  // multiple of 4
    hcnt[lane] = c;
    boff[lane] = start;
    wcur[0][lane] = start;
    wcur[1][lane] = start + h0;
    wcur[2][lane] = start + h0 + h1;
    wcur[3][lane] = start + h0 + h1 + h2;
    for (int t2 = c; t2 < p4; ++t2) ids[start + t2] = N_NODES;  // 0x80 row
  }
  __syncthreads();

#pragma unroll
  for (int k = 0; k < 5; ++k) {
    if (entv[k] != 0xFFFFFFFFu) {
      int dl = entv[k] >> 17;
      int pos = atomicAdd(&wcur[w][dl], 1);
      ids[pos] = (int)(entv[k] & 0x1FFFFu);
    }
  }
  __syncthreads();

  // ---- gather: 4-lane group g owns node w*16+g; 16 feats (16B) per lane ---
  {
    const int q4 = lane & 3;   // feature quarter: features 16q4 .. 16q4+15
    const int g = lane >> 2;   // group 0..15 = local node row
    const int row = w * 16 + g;
    const int dgv = hcnt[row];
    const int off = boff[row];  // multiple of 4
    const int dg4 = (dgv + 3) & ~3;
    uint a[16];
#pragma unroll
    for (int k = 0; k < 16; ++k) a[k] = 0u;

#define ACCQ(Q)                                                         \
    a[0] += Q.x & 255u;         a[1] += (Q.x >> 8) & 255u;              \
    a[2] += (Q.x >> 16) & 255u; a[3] += Q.x >> 24;                      \
    a[4] += Q.y & 255u;         a[5] += (Q.y >> 8) & 255u;              \
    a[6] += (Q.y >> 16) & 255u; a[7] += Q.y >> 24;                      \
    a[8] += Q.z & 255u;         a[9] += (Q.z >> 8) & 255u;              \
    a[10] += (Q.z >> 16) & 255u; a[11] += Q.z >> 24;                    \
    a[12] += Q.w & 255u;        a[13] += (Q.w >> 8) & 255u;             \
    a[14] += (Q.w >> 16) & 255u; a[15] += Q.w >> 24;

    for (int j = 0; j < dg4; j += 4) {
      int4 sv = *(const int4*)&ids[off + j];  // one ds_read_b128
      uint4 q0 = xq4[(uint)sv.x * 4u + (uint)q4];
      uint4 q1 = xq4[(uint)sv.y * 4u + (uint)q4];
      uint4 q2 = xq4[(uint)sv.z * 4u + (uint)q4];
      uint4 q3 = xq4[(uint)sv.w * 4u + (uint)q4];
      ACCQ(q0);
      ACCQ(q1);
      ACCQ(q2);
      ACCQ(q3);
    }
#undef ACCQ

    // un-bias: every summed byte (incl. 0x80 pads) carries +128.
    float bias = 128.0f * (float)dg4;
    float scale = (1.0f / 32.0f) / fmaxf((float)dgv, 1.0f);
    uint o[8];
#pragma unroll
    for (int k = 0; k < 8; ++k)
      o[k] = ((uint)f2bf(((float)a[2 * k + 1] - bias) * scale) << 16) |
             f2bf(((float)a[2 * k] - bias) * scale);
    *(uint4*)&smean[w][g * 36 + q4 * 8] = make_uint4(o[0], o[1], o[2], o[3]);
    *(uint4*)&smean[w][g * 36 + q4 * 8 + 4] = make_uint4(o[4], o[5], o[6], o[7]);
  }
  // smean slab is per-wave -> no barrier needed before MFMA.

  // ---- load prepacked B-fragments (16 x dwordx4, L2-hot) ----
  short8 bf[2][4][2];
#pragma unroll
  for (int mat = 0; mat < 2; ++mat)
#pragma unroll
    for (int ct = 0; ct < 4; ++ct)
#pragma unroll
      for (int kk = 0; kk < 2; ++kk) {
        uint4 v = wfrag[((mat * 4 + ct) * 2 + kk) * 64 + lane];
        bf[mat][ct][kk] = *(short8*)&v;
      }

  // ---- MFMA transform: wave w -> 16-node tile; fp32 h direct to d_out ----
  const int r16 = lane & 15;
  const int kg = lane >> 4;
  const int gn0 = bid * BK + w * 16;
  float psum[4] = {0.f, 0.f, 0.f, 0.f};
  float psq[4] = {0.f, 0.f, 0.f, 0.f};

  if (gn0 < N_NODES) {
    short8 am0 = *(const short8*)&smean[w][r16 * 36 + kg * 4];
    short8 am1 = *(const short8*)&smean[w][r16 * 36 + 16 + kg * 4];
    const short8* xbf = (const short8*)xb;
    short8 ax0 = xbf[(size_t)(gn0 + r16) * 8 + kg];
    short8 ax1 = xbf[(size_t)(gn0 + r16) * 8 + 4 + kg];

#pragma unroll
    for (int ct = 0; ct < 4; ++ct) {
      float bias = bl[ct * 16 + r16];
      f32x4 acc = {0.f, 0.f, 0.f, 0.f};
      acc = __builtin_amdgcn_mfma_f32_16x16x32_bf16(am0, bf[0][ct][0], acc, 0, 0, 0);
      acc = __builtin_amdgcn_mfma_f32_16x16x32_bf16(am1, bf[0][ct][1], acc, 0, 0, 0);
      acc = __builtin_amdgcn_mfma_f32_16x16x32_bf16(ax0, bf[1][ct][0], acc, 0, 0, 0);
      acc = __builtin_amdgcn_mfma_f32_16x16x32_bf16(ax1, bf[1][ct][1], acc, 0, 0, 0);
#pragma unroll
      for (int r = 0; r < 4; ++r) {
        float hv = fmaxf(acc[r] + bias, 0.f);
        hout[(size_t)(gn0 + kg * 4 + r) * D + ct * 16 + r16] = hv;
        psum[ct] += hv;
        psq[ct] += hv * hv;
      }
    }
  }

  // ---- BN partial merge ----
#pragma unroll
  for (int ct = 0; ct < 4; ++ct) {
    float v1 = psum[ct], v2 = psq[ct];
    v1 += __shfl_xor(v1, 16, 64); v1 += __shfl_xor(v1, 32, 64);
    v2 += __shfl_xor(v2, 16, 64); v2 += __shfl_xor(v2, 32, 64);
    if (lane < 16) {
      atomicAdd(&bsum[ct * 16 + lane], v1);
      atomicAdd(&bsq[ct * 16 + lane], v2);
    }
  }
  __syncthreads();
  if (tid < D) {
    float* srep = sums + (size_t)(bid & (NREP - 1)) * 128;
    atomicAdd(&srep[tid], bsum[tid]);
    atomicAdd(&srep[D + tid], bsq[tid]);
  }
}

// ---------------------------------------------------------------------------
// finalize: reduce BN replicas -> scale/shift; out = x + h*scale + shift.
// h is fp32 in d_out (updated in place, thread-local); x residual from bf16.
// ---------------------------------------------------------------------------
__global__ __launch_bounds__(256) void finalize_kernel(
    const uint4* __restrict__ xb4,
    const float* __restrict__ sums,
    const float* __restrict__ gamma,
    const float* __restrict__ beta,
    float* __restrict__ out) {
  __shared__ float ssc[D], ssh[D];
  const int tid = threadIdx.x;
  if (tid < D) {
    float s = 0.f, q = 0.f;
#pragma unroll
    for (int r = 0; r < NREP; ++r) {
      s += sums[r * 128 + tid];
      q += sums[r * 128 + D + tid];
    }
    float mu = s / (float)N_NODES;
    float var = q / (float)N_NODES - mu * mu;
    float inv = rsqrtf(fmaxf(var, 0.f) + BN_EPS);
    float sc = gamma[tid] * inv;
    ssc[tid] = sc;
    ssh[tid] = beta[tid] - mu * sc;
  }
  __syncthreads();
  const int total = N_NODES * D / 8;  // 8 feats per thread
  int i = blockIdx.x * 256 + tid;
  if (i >= total) return;
  int u8 = i & 7;
  float4 sa = *(const float4*)&ssc[u8 * 8];
  float4 sb = *(const float4*)&ssc[u8 * 8 + 4];
  float4 ha = *(const float4*)&ssh[u8 * 8];
  float4 hbv = *(const float4*)&ssh[u8 * 8 + 4];
  float4 h0 = ((const float4*)out)[i * 2];      // thread-local in-place
  float4 h1 = ((const float4*)out)[i * 2 + 1];
  uint4 xv = xb4[i];
  float4 r0, r1;
  r0.x = __uint_as_float(xv.x << 16) + h0.x * sa.x + ha.x;
  r0.y = __uint_as_float(xv.x & 0xffff0000u) + h0.y * sa.y + ha.y;
  r0.z = __uint_as_float(xv.y << 16) + h0.z * sa.z + ha.z;
  r0.w = __uint_as_float(xv.y & 0xffff0000u) + h0.w * sa.w + ha.w;
  r1.x = __uint_as_float(xv.z << 16) + h1.x * sb.x + hbv.x;
  r1.y = __uint_as_float(xv.z & 0xffff0000u) + h1.y * sb.y + hbv.y;
  r1.z = __uint_as_float(xv.w << 16) + h1.z * sb.z + hbv.z;
  r1.w = __uint_as_float(xv.w & 0xffff0000u) + h1.w * sb.w + hbv.w;
  ((float4*)out)[i * 2] = r0;
  ((float4*)out)[i * 2 + 1] = r1;
}

extern "C" void kernel_launch(void* const* d_in, const int* in_sizes, int n_in,
                              void* d_out, int out_size, void* d_ws, size_t ws_size,
                              hipStream_t stream) {
  const float* x     = (const float*)d_in[0];
  const int*   ei    = (const int*)d_in[1];
  const float* Wl    = (const float*)d_in[2];
  const float* bl    = (const float*)d_in[3];
  const float* Wr    = (const float*)d_in[4];
  const float* gamma = (const float*)d_in[5];
  const float* beta  = (const float*)d_in[6];
  float* out = (float*)d_out;

  // workspace layout (4B units); zeroed region first; 16B alignment kept.
  // NO buffer follows xq (r11/r14/r15 bug: h-buffer overflow clobbered xq).
  int* ccur   = (int*)d_ws;                        // NC*CSTRIDE  (zeroed)
  int* fcur   = ccur + NC * CSTRIDE;               // NB*CSTRIDE  (zeroed)
  float* sums = (float*)(fcur + NB * CSTRIDE);     // NREP*128    (zeroed)
  uint* cstg  = (uint*)(sums + NREP * 128);        // NC*CAPC
  uint* fstg  = cstg + (size_t)NC * CAPC;          // NB*FCAP
  uint* xb    = fstg + (size_t)NB * FCAP;          // (N+1)*32
  uint* wfrag = xb + (size_t)(N_NODES + 1) * 32;   // 1024*4 (B-frag table)
  uint* xq    = wfrag + 1024 * 4;                  // (N+1)*16 (u8 rows), LAST

  zero_kernel<<<(NZERO / 4 + 255) / 256, 256, 0, stream>>>((uint4*)d_ws);
  passA_kernel<<<ABLOCKS, 256, 0, stream>>>(x, ei, Wl, Wr, ccur, cstg,
                                            (uint4*)xb, (uint2*)xq,
                                            (uint4*)wfrag);
  passB_kernel<<<NC * BCH, 256, 0, stream>>>(cstg, ccur, fcur, fstg);
  bucket_bin_gather_mfma_kernel<<<NB, 256, 0, stream>>>(
      xb, (const uint4*)xq, fstg, fcur, (const uint4*)wfrag, bl, out, sums);
  finalize_kernel<<<(N_NODES * D / 8 + 255) / 256, 256, 0, stream>>>(
      (const uint4*)xb, sums, gamma, beta, out);
}